// Round 3
// baseline (2014.806 us; speedup 1.0000x reference)
//
#include <hip/hip_runtime.h>
#include <hip/hip_bf16.h>

#define V_SZ 100000
#define E_SZ 128
#define H_SZ 512
#define L_SZ 9
#define B_SZ 64
#define T_SZ 512
#define G4   (4*H_SZ)

#define LOGITS_N (B_SZ*T_SZ*L_SZ)            // 294912
#define HS_BYTES ((size_t)B_SZ*T_SZ*H_SZ*2)  // 33554432
#define SENT32 0x7FC07FC0u
#define SENT64 0x7FC07FC07FC07FC0ull

typedef short bf16x8 __attribute__((ext_vector_type(8)));
typedef float f32x4  __attribute__((ext_vector_type(4)));

static __device__ __forceinline__ unsigned short f2bf(float x){
  unsigned int u = __builtin_bit_cast(unsigned int, x);
  unsigned int r = (u + 0x7fffu + ((u >> 16) & 1u)) >> 16;
  return (unsigned short)r;
}
static __device__ __forceinline__ float bf2f(unsigned short b){
  unsigned int u = ((unsigned int)b) << 16;
  return __builtin_bit_cast(float, u);
}
static __device__ __forceinline__ float sig_f(float x){
  return 1.f / (1.f + __expf(-x));
}
static __device__ __forceinline__ float tanh_f(float x){
  float a = fabsf(x);
  float e = __expf(-2.f * a);
  float t = (1.f - e) / (1.f + e);
  return copysignf(t, x);
}

// ---------------- reset hs to sentinel (graph replays don't re-poison) ------
__global__ void k_reset(unsigned long long* __restrict__ hs64){
  const long n = HS_BYTES / 8;
  for (long i = (long)blockIdx.x*256 + threadIdx.x; i < n; i += (long)gridDim.x*256)
    __hip_atomic_store(&hs64[i], SENT64, __ATOMIC_RELAXED, __HIP_MEMORY_SCOPE_AGENT);
}

// ---------------- lens ----------------
__global__ void k_lens(const int* __restrict__ text, float* __restrict__ out_lens){
  int b = blockIdx.x;
  int c = 0;
  for (int t = threadIdx.x; t < T_SZ; t += 256)
    c += (text[b*T_SZ + t] != 0);
  for (int off = 32; off; off >>= 1) c += __shfl_down(c, off, 64);
  __shared__ int sred[4];
  int w = threadIdx.x >> 6;
  if ((threadIdx.x & 63) == 0) sred[w] = c;
  __syncthreads();
  if (threadIdx.x == 0)
    out_lens[b] = (float)(sred[0] + sred[1] + sred[2] + sred[3]);
}

// ---------------- fused embed + xg + LSTM recurrence ----------------
// 4 pairs x 32 blocks; block handles TWO sequence-groups (A,B) of 8 seqs each,
// interleaved so each chain's LLC publish latency hides under the other
// chain's compute. Block j owns h-columns [16j,16j+16) for both chains.
// Publish: packed 2xbf16 relaxed agent (sc1) stores; consumers poll the data
// itself against a NaN sentinel (h = sig*tanh can never be NaN). No fences,
// no flags, no vmcnt drain anywhere in the loop.
__global__ __launch_bounds__(256, 1)
void k_lstm(const int* __restrict__ text, const float* __restrict__ embed,
            const float* __restrict__ Wx, const float* __restrict__ Wh,
            const float* __restrict__ bias, unsigned short* __restrict__ hs)
{
  const int p    = blockIdx.x & 3;     // pair id
  const int j    = blockIdx.x >> 2;    // 0..31 block-in-pair
  const int gA   = 2*p, gB = 2*p + 1;  // the two sequence-groups
  const int n0   = j * 16;             // owned h-columns [n0, n0+16)
  const int tid  = threadIdx.x;
  const int w    = tid >> 6;           // wave = gate quadrant (i,f,cg,o)
  const int lane = tid & 63;
  const int q    = lane >> 4;
  const int l16  = lane & 15;

  __shared__ unsigned short h_lds[16*512];   // 16 KB, XOR-swizzled, rows 8-15 zero
  __shared__ unsigned short x_lds[16*128];   // 4 KB, XOR-swizzled, rows 8-15 zero
  __shared__ float gate_lds[4][8][16];       // 2 KB
  // (shared by both chains; barriers order reuse)

  for (int i = tid; i < 16*512; i += 256) h_lds[i] = 0;
  for (int i = tid; i < 16*128; i += 256) x_lds[i] = 0;

  // Preload weight B-frags (bf16), shared by both chains.
  // B elem jj of k-chunk kk: W[(kk*32 + q*8 + jj)][gcol]
  const int gcol = w * H_SZ + n0 + l16;
  bf16x8 Whf[16];
#pragma unroll
  for (int kk = 0; kk < 16; ++kk){
    bf16x8 v;
#pragma unroll
    for (int jj = 0; jj < 8; ++jj)
      v[jj] = (short)f2bf(Wh[(long)(kk*32 + q*8 + jj)*G4 + gcol]);
    Whf[kk] = v;
  }
  bf16x8 Wxf[4];
#pragma unroll
  for (int kk = 0; kk < 4; ++kk){
    bf16x8 v;
#pragma unroll
    for (int jj = 0; jj < 8; ++jj)
      v[jj] = (short)f2bf(Wx[(long)(kk*32 + q*8 + jj)*G4 + gcol]);
    Wxf[kk] = v;
  }
  const float biasv = bias[gcol];

  // c-state held by wave 0: lane -> (row gr, cols gc2, gc2+1), per chain
  float csA0 = 0.f, csA1 = 0.f, csB0 = 0.f, csB1 = 0.f;
  const int gr  = tid >> 3;           // 0..7 (valid for tid<64)
  const int gc2 = (tid & 7) * 2;

  // poll-stage mapping: thread covers 4 chunks of 8B
  const int k4     = tid & 127;       // 8B-chunk column (cols k4*4 .. +3)
  const int hrbase = tid >> 7;        // 0 or 1

  __syncthreads();

  auto phase = [&](int g, int t, float& cs0, float& cs1){
    // ---- stage x_t (embed gather -> bf16 -> swizzled LDS) ----
    {
      int xr = tid >> 5;                    // 0..7 (batch row)
      int c4 = (tid & 31) * 4;              // f32 column
      int idx = text[(g*8 + xr)*T_SZ + t];
      const float4 xv = *(const float4*)(embed + (long)idx*E_SZ + c4);
      int cb = c4 * 2;
      unsigned short* pp = (unsigned short*)((char*)x_lds + xr*256 + (cb ^ (xr << 4)));
      pp[0] = f2bf(xv.x); pp[1] = f2bf(xv.y); pp[2] = f2bf(xv.z); pp[3] = f2bf(xv.w);
    }

    if (t > 0){
      // ---- poll h_{t-1} directly (data is the flag), then stage to LDS ----
      unsigned long long v[4];
      int it = 0; bool ok;
      do {
        ok = true;
#pragma unroll
        for (int c = 0; c < 4; ++c){
          int hrow = hrbase + 2*c;
          v[c] = __hip_atomic_load(
              (const unsigned long long*)(hs + ((long)(g*8 + hrow)*T_SZ + (t-1))*H_SZ + k4*4),
              __ATOMIC_RELAXED, __HIP_MEMORY_SCOPE_AGENT);
        }
#pragma unroll
        for (int c = 0; c < 4; ++c){
          unsigned int lo = (unsigned int)v[c], hi = (unsigned int)(v[c] >> 32);
          ok = ok && (lo != SENT32) && (hi != SENT32);
        }
      } while (!ok && ++it < (1 << 20));
#pragma unroll
      for (int c = 0; c < 4; ++c){
        int hrow = hrbase + 2*c;
        *(unsigned long long*)((char*)h_lds + hrow*1024 + ((k4*8) ^ (hrow << 4))) = v[c];
      }
    }
    __syncthreads();     // B2: x_lds + h_lds staged; prev gate_lds fully consumed

    // ---- MFMA: C = x_t @ Wx (+ h_{t-1} @ Wh) ----
    f32x4 acc0 = {0.f,0.f,0.f,0.f}, acc1 = {0.f,0.f,0.f,0.f};
#pragma unroll
    for (int kk = 0; kk < 4; ++kk){
      bf16x8 a = *(const bf16x8*)((const char*)x_lds + l16*256 + ((kk*64 + q*16) ^ (l16 << 4)));
      if (kk & 1) acc1 = __builtin_amdgcn_mfma_f32_16x16x32_bf16(a, Wxf[kk], acc1, 0, 0, 0);
      else        acc0 = __builtin_amdgcn_mfma_f32_16x16x32_bf16(a, Wxf[kk], acc0, 0, 0, 0);
    }
    if (t > 0){
#pragma unroll
      for (int kk = 0; kk < 16; ++kk){
        bf16x8 a = *(const bf16x8*)((const char*)h_lds + l16*1024 + ((kk*64 + q*16) ^ (l16 << 4)));
        if (kk & 1) acc1 = __builtin_amdgcn_mfma_f32_16x16x32_bf16(a, Whf[kk], acc1, 0, 0, 0);
        else        acc0 = __builtin_amdgcn_mfma_f32_16x16x32_bf16(a, Whf[kk], acc0, 0, 0, 0);
      }
    }
    // C/D layout: col = lane&15, row = (lane>>4)*4 + reg (rows 0..7 valid)
#pragma unroll
    for (int rg = 0; rg < 4; ++rg){
      int row = q*4 + rg;
      if (row < 8) gate_lds[w][row][l16] = acc0[rg] + acc1[rg] + biasv;
    }
    __syncthreads();     // B3: gate_lds ready; h_lds/x_lds free for next phase

    // ---- gates -> (c,h); wave 0 publishes h (data is the flag) ----
    if (tid < 64){
      float gi0 = gate_lds[0][gr][gc2], gi1 = gate_lds[0][gr][gc2+1];
      float gf0 = gate_lds[1][gr][gc2], gf1 = gate_lds[1][gr][gc2+1];
      float gg0 = gate_lds[2][gr][gc2], gg1 = gate_lds[2][gr][gc2+1];
      float go0 = gate_lds[3][gr][gc2], go1 = gate_lds[3][gr][gc2+1];
      cs0 = sig_f(gf0)*cs0 + sig_f(gi0)*tanh_f(gg0);
      cs1 = sig_f(gf1)*cs1 + sig_f(gi1)*tanh_f(gg1);
      float h0 = sig_f(go0)*tanh_f(cs0);
      float h1 = sig_f(go1)*tanh_f(cs1);
      unsigned int pk = (unsigned int)f2bf(h0) | ((unsigned int)f2bf(h1) << 16);
      __hip_atomic_store(
          (unsigned int*)(hs + ((long)(g*8 + gr)*T_SZ + t)*H_SZ + n0 + gc2), pk,
          __ATOMIC_RELAXED, __HIP_MEMORY_SCOPE_AGENT);
    }
    // no barrier: waves 1-3 run ahead into the other chain's staging
  };

  for (int t = 0; t < T_SZ; ++t){
    phase(gA, t, csA0, csA1);
    phase(gB, t, csB0, csB1);
  }
}

// ---------------- logits = hs @ Wd + bd ----------------
__global__ void k_logits(const unsigned short* __restrict__ hs,
                         const float* __restrict__ Wd, const float* __restrict__ bd,
                         float* __restrict__ out)
{
  __shared__ float wd_s[H_SZ*L_SZ];
  __shared__ float bd_s[L_SZ];
  for (int i = threadIdx.x; i < H_SZ*L_SZ; i += 128) wd_s[i] = Wd[i];
  if (threadIdx.x < L_SZ) bd_s[threadIdx.x] = bd[threadIdx.x];
  __syncthreads();

  long row = (long)blockIdx.x*128 + threadIdx.x;   // 0..32767
  const unsigned short* hp = hs + row*H_SZ;
  float acc[9];
#pragma unroll
  for (int jj = 0; jj < 9; ++jj) acc[jj] = 0.f;
  for (int k = 0; k < H_SZ; k += 8){
    uint4 v = *(const uint4*)(hp + k);
    const unsigned short* u = (const unsigned short*)&v;
#pragma unroll
    for (int l = 0; l < 8; ++l){
      float hf = bf2f(u[l]);
#pragma unroll
      for (int jj = 0; jj < 9; ++jj)
        acc[jj] = fmaf(hf, wd_s[(k + l)*L_SZ + jj], acc[jj]);
    }
  }
  float* op = out + row*L_SZ;
#pragma unroll
  for (int jj = 0; jj < 9; ++jj) op[jj] = acc[jj] + bd_s[jj];
}

// ---------------- CRF: score + forward algorithm ----------------
__global__ void k_crf(const float* __restrict__ logits, const int* __restrict__ labels,
                      const float* __restrict__ trans, const float* __restrict__ lensf,
                      float* __restrict__ out_ll)
{
  int b = blockIdx.x;
  int lane = threadIdx.x;             // 64 threads = 1 wave
  int len = (int)lensf[b];
  const float* lg  = logits + (long)b*T_SZ*L_SZ;
  const int*   lab = labels + b*T_SZ;

  float s = 0.f;
  for (int t = lane; t < T_SZ; t += 64){
    if (t < len){
      s += lg[t*L_SZ + lab[t]];
      if (t >= 1) s += trans[lab[t-1]*L_SZ + lab[t]];
    }
  }
  for (int off = 32; off; off >>= 1) s += __shfl_down(s, off, 64);

  float tr[9];
#pragma unroll
  for (int i = 0; i < 9; ++i) tr[i] = (lane < 9) ? trans[i*L_SZ + lane] : 0.f;
  float alpha = (lane < 9) ? lg[lane] : -1e30f;

  for (int t = 1; t < T_SZ; ++t){
    float tmp[9];
#pragma unroll
    for (int i = 0; i < 9; ++i){
      float ai = __shfl(alpha, i, 64);
      tmp[i] = ai + tr[i];
    }
    float m0 = fmaxf(fmaxf(tmp[0], tmp[1]), tmp[2]);
    float m1 = fmaxf(fmaxf(tmp[3], tmp[4]), tmp[5]);
    float m2 = fmaxf(fmaxf(tmp[6], tmp[7]), tmp[8]);
    float m  = fmaxf(fmaxf(m0, m1), m2);
    float e = 0.f;
#pragma unroll
    for (int i = 0; i < 9; ++i) e += __expf(tmp[i] - m);
    float lgv = (lane < 9) ? lg[t*L_SZ + lane] : 0.f;
    float nv = m + __logf(e) + lgv;
    if (t < len && lane < 9) alpha = nv;
  }

  float mm = (lane < 9) ? alpha : -1e30f;
  for (int off = 8; off; off >>= 1) mm = fmaxf(mm, __shfl_down(mm, off, 64));
  mm = __shfl(mm, 0, 64);
  float ee = (lane < 9) ? __expf(alpha - mm) : 0.f;
  for (int off = 8; off; off >>= 1) ee += __shfl_down(ee, off, 64);
  if (lane == 0) out_ll[b] = s - (mm + __logf(ee));
}

extern "C" void kernel_launch(void* const* d_in, const int* in_sizes, int n_in,
                              void* d_out, int out_size, void* d_ws, size_t ws_size,
                              hipStream_t stream)
{
  const int*   text   = (const int*)  d_in[0];
  const int*   labels = (const int*)  d_in[1];
  const float* embed  = (const float*)d_in[2];
  const float* Wx     = (const float*)d_in[3];
  const float* Wh     = (const float*)d_in[4];
  const float* bias   = (const float*)d_in[5];
  const float* Wd     = (const float*)d_in[6];
  const float* bd     = (const float*)d_in[7];
  const float* trans  = (const float*)d_in[8];

  float* out        = (float*)d_out;
  float* out_logits = out;
  float* out_lens   = out + LOGITS_N;
  float* out_ll     = out + LOGITS_N + B_SZ;

  unsigned short* hs = (unsigned short*)d_ws;

  k_reset <<<2048, 256, 0, stream>>>((unsigned long long*)hs);
  k_lens  <<<B_SZ, 256, 0, stream>>>(text, out_lens);
  k_lstm  <<<128, 256, 0, stream>>>(text, embed, Wx, Wh, bias, hs);
  k_logits<<<256, 128, 0, stream>>>(hs, Wd, bd, out_logits);
  k_crf   <<<B_SZ, 64, 0, stream>>>(out_logits, labels, trans, out_lens, out_ll);
}

// Round 6
// 1576.926 us; speedup vs baseline: 1.2777x; 1.2777x over previous
//
#include <hip/hip_runtime.h>
#include <hip/hip_bf16.h>

#define V_SZ 100000
#define E_SZ 128
#define H_SZ 512
#define L_SZ 9
#define B_SZ 64
#define T_SZ 512
#define G4   (4*H_SZ)

#define LOGITS_N (B_SZ*T_SZ*L_SZ)            // 294912
#define HS_BYTES ((size_t)B_SZ*T_SZ*H_SZ*2)  // 33554432
#define SENT32 0x7FC07FC0u
#define SENT64 0x7FC07FC07FC07FC0ull

typedef short bf16x8 __attribute__((ext_vector_type(8)));
typedef float f32x4  __attribute__((ext_vector_type(4)));

static __device__ __forceinline__ unsigned short f2bf(float x){
  unsigned int u = __builtin_bit_cast(unsigned int, x);
  unsigned int r = (u + 0x7fffu + ((u >> 16) & 1u)) >> 16;
  return (unsigned short)r;
}
static __device__ __forceinline__ float bf2f(unsigned short b){
  unsigned int u = ((unsigned int)b) << 16;
  return __builtin_bit_cast(float, u);
}
static __device__ __forceinline__ float sig_f(float x){
  return 1.f / (1.f + __expf(-x));
}
static __device__ __forceinline__ float tanh_f(float x){
  float a = fabsf(x);
  float e = __expf(-2.f * a);
  float t = (1.f - e) / (1.f + e);
  return copysignf(t, x);
}

// ---------------- reset hs to sentinel (graph replays don't re-poison) ------
__global__ void k_reset(unsigned long long* __restrict__ hs64){
  const long n = HS_BYTES / 8;
  for (long i = (long)blockIdx.x*256 + threadIdx.x; i < n; i += (long)gridDim.x*256)
    __hip_atomic_store(&hs64[i], SENT64, __ATOMIC_RELAXED, __HIP_MEMORY_SCOPE_AGENT);
}

// ---------------- lens ----------------
__global__ void k_lens(const int* __restrict__ text, float* __restrict__ out_lens){
  int b = blockIdx.x;
  int c = 0;
  for (int t = threadIdx.x; t < T_SZ; t += 256)
    c += (text[b*T_SZ + t] != 0);
  for (int off = 32; off; off >>= 1) c += __shfl_down(c, off, 64);
  __shared__ int sred[4];
  int w = threadIdx.x >> 6;
  if ((threadIdx.x & 63) == 0) sred[w] = c;
  __syncthreads();
  if (threadIdx.x == 0)
    out_lens[b] = (float)(sred[0] + sred[1] + sred[2] + sred[3]);
}

// ---------------- fused embed + xg + LSTM recurrence ----------------
// r2's proven block structure + coherence ops, with the permuted B-fragment
// layout so all 4 gates of an h-column live in ONE wave:
//   B-column l16 -> (gate = l16&3, h-col = n0 + 4w + (l16>>2)).
// After MFMA, 3 quad-shuffles combine gates in-register; each wave publishes
// its own 4 h-columns with relaxed agent 4B stores (data-is-flag, bf16-NaN
// sentinel). h/x LDS double-buffered by step parity -> ONE barrier per step,
// no gate_lds, no serial section. Poll/stage of h_{t-1}: r2 code verbatim.
__global__ __launch_bounds__(256, 1)
void k_lstm(const int* __restrict__ text, const float* __restrict__ embed,
            const float* __restrict__ Wx, const float* __restrict__ Wh,
            const float* __restrict__ bias, unsigned short* __restrict__ hs)
{
  const int g    = blockIdx.x & 7;     // group (intended XCD under round-robin)
  const int j    = blockIdx.x >> 3;    // 0..31 block-in-group
  const int n0   = j * 16;             // owned h-columns [n0, n0+16)
  const int tid  = threadIdx.x;
  const int w    = tid >> 6;           // wave id
  const int lane = tid & 63;
  const int q    = lane >> 4;
  const int l16  = lane & 15;
  const int gate = l16 & 3;            // B-col -> gate
  const int cq   = l16 >> 2;           // B-col -> col-in-wave 0..3

  __shared__ unsigned short h_lds[2][16*512];   // 2 x 16 KB, swizzled, rows 8-15 zero
  __shared__ unsigned short x_lds[2][16*128];   // 2 x 4 KB,  swizzled, rows 8-15 zero

  for (int i = tid; i < 2*16*512; i += 256) ((unsigned short*)h_lds)[i] = 0;
  for (int i = tid; i < 2*16*128; i += 256) ((unsigned short*)x_lds)[i] = 0;

  // ---- weight B-frags (permuted): W[(kk*32 + q*8 + jj)][gate*H + hcol] ----
  const int hcol = n0 + w*4 + cq;
  const int gcol = gate*H_SZ + hcol;
  bf16x8 Whf[16];
#pragma unroll
  for (int kk = 0; kk < 16; ++kk){
    bf16x8 v;
#pragma unroll
    for (int jj = 0; jj < 8; ++jj)
      v[jj] = (short)f2bf(Wh[(long)(kk*32 + q*8 + jj)*G4 + gcol]);
    Whf[kk] = v;
  }
  bf16x8 Wxf[4];
#pragma unroll
  for (int kk = 0; kk < 4; ++kk){
    bf16x8 v;
#pragma unroll
    for (int jj = 0; jj < 8; ++jj)
      v[jj] = (short)f2bf(Wx[(long)(kk*32 + q*8 + jj)*G4 + gcol]);
    Wxf[kk] = v;
  }
  const float biasv = bias[gcol];

  // c-state: rows q*4+rg of the wave's 4 columns (valid/used for q<2);
  // redundant across the 4 gate-lanes of each column -> identical arithmetic.
  float cs[4] = {0.f, 0.f, 0.f, 0.f};
  const bool isPub = (gate == 0) && ((cq & 1) == 0) && (q < 2);

  unsigned short* ppub[4];
#pragma unroll
  for (int rg = 0; rg < 4; ++rg)
    ppub[rg] = hs + ((long)(g*8 + q*4 + rg)*T_SZ)*H_SZ + n0 + w*4 + cq;

  __syncthreads();

  for (int t = 0; t < T_SZ; ++t){
    const int par = t & 1;

    // ---- stage x_t (embed gather -> bf16 -> swizzled LDS) ----
    {
      int xr = tid >> 5;                    // 0..7 (batch row)
      int c4 = (tid & 31) * 4;              // f32 column
      int idx = text[(g*8 + xr)*T_SZ + t];
      const float4 xv = *(const float4*)(embed + (long)idx*E_SZ + c4);
      int cb = c4 * 2;
      unsigned short* pp = (unsigned short*)((char*)x_lds[par] + xr*256 + (cb ^ (xr << 4)));
      pp[0] = f2bf(xv.x); pp[1] = f2bf(xv.y); pp[2] = f2bf(xv.z); pp[3] = f2bf(xv.w);
    }

    if (t > 0){
      // ---- poll h_{t-1} (data is the flag), then stage to LDS (r2 verbatim) ----
      unsigned long long v[4];
      int it = 0; bool ok;
      do {
        ok = true;
#pragma unroll
        for (int c = 0; c < 4; ++c){
          int chunk = tid + 256*c;            // 0..1023
          int hr    = chunk >> 7;             // 0..7
          int k4    = chunk & 127;            // 8B chunk -> cols k4*4
          v[c] = __hip_atomic_load(
              (const unsigned long long*)(hs + ((long)(g*8 + hr)*T_SZ + (t-1))*H_SZ + k4*4),
              __ATOMIC_RELAXED, __HIP_MEMORY_SCOPE_AGENT);
        }
#pragma unroll
        for (int c = 0; c < 4; ++c){
          unsigned int lo = (unsigned int)v[c], hi = (unsigned int)(v[c] >> 32);
          ok = ok && (lo != SENT32) && (hi != SENT32);
        }
      } while (!ok && ++it < (1 << 20));
#pragma unroll
      for (int c = 0; c < 4; ++c){
        int chunk = tid + 256*c;
        int hr    = chunk >> 7;
        int k4    = chunk & 127;
        *(unsigned long long*)((char*)h_lds[par] + hr*1024 + ((k4*8) ^ (hr << 4))) = v[c];
      }
    }
    __syncthreads();   // the ONLY barrier: staging done; prev step's reads done
                       // (parity buffers make cross-step write/read disjoint)

    // ---- MFMA: gates = x_t @ Wx (+ h_{t-1} @ Wh) + b ----
    f32x4 acc0 = {biasv, biasv, biasv, biasv};
    f32x4 acc1 = {0.f, 0.f, 0.f, 0.f};
#pragma unroll
    for (int kk = 0; kk < 4; ++kk){
      bf16x8 a = *(const bf16x8*)((const char*)x_lds[par] + l16*256 + ((kk*64 + q*16) ^ (l16 << 4)));
      if (kk & 1) acc1 = __builtin_amdgcn_mfma_f32_16x16x32_bf16(a, Wxf[kk], acc1, 0, 0, 0);
      else        acc0 = __builtin_amdgcn_mfma_f32_16x16x32_bf16(a, Wxf[kk], acc0, 0, 0, 0);
    }
    if (t > 0){
#pragma unroll
      for (int kk = 0; kk < 16; ++kk){
        bf16x8 a = *(const bf16x8*)((const char*)h_lds[par] + l16*1024 + ((kk*64 + q*16) ^ (l16 << 4)));
        if (kk & 1) acc1 = __builtin_amdgcn_mfma_f32_16x16x32_bf16(a, Whf[kk], acc1, 0, 0, 0);
        else        acc0 = __builtin_amdgcn_mfma_f32_16x16x32_bf16(a, Whf[kk], acc0, 0, 0, 0);
      }
    }

    // ---- gates via quad shuffles; c,h; publish (data-is-flag) ----
    // C/D: col = l16 -> (gate, cq); row = q*4+rg. xor-k neighbor holds gate^k.
#pragma unroll
    for (int rg = 0; rg < 4; ++rg){
      float v  = acc0[rg] + acc1[rg];
      float x1 = __shfl_xor(v, 1, 64);
      float x2 = __shfl_xor(v, 2, 64);
      float x3 = __shfl_xor(v, 3, 64);
      float gi = (gate==0)? v : (gate==1)? x1 : (gate==2)? x2 : x3;
      float gf = (gate==1)? v : (gate==0)? x1 : (gate==3)? x2 : x3;
      float gc = (gate==2)? v : (gate==3)? x1 : (gate==0)? x2 : x3;
      float go = (gate==3)? v : (gate==2)? x1 : (gate==1)? x2 : x3;
      cs[rg] = sig_f(gf)*cs[rg] + sig_f(gi)*tanh_f(gc);
      float hv = sig_f(go)*tanh_f(cs[rg]);
      unsigned int hb = (unsigned int)f2bf(hv);
      unsigned int pr = (unsigned int)__shfl_xor((int)hb, 4, 64);  // col cq^1
      unsigned int pk = hb | (pr << 16);
      if (isPub)
        __hip_atomic_store((unsigned int*)ppub[rg], pk,
                           __ATOMIC_RELAXED, __HIP_MEMORY_SCOPE_AGENT);
    }
#pragma unroll
    for (int rg = 0; rg < 4; ++rg) ppub[rg] += H_SZ;
    // no trailing barrier: next iteration writes the OTHER parity buffers
  }
}

// ---------------- logits = hs @ Wd + bd ----------------
__global__ void k_logits(const unsigned short* __restrict__ hs,
                         const float* __restrict__ Wd, const float* __restrict__ bd,
                         float* __restrict__ out)
{
  __shared__ float wd_s[H_SZ*L_SZ];
  __shared__ float bd_s[L_SZ];
  for (int i = threadIdx.x; i < H_SZ*L_SZ; i += 128) wd_s[i] = Wd[i];
  if (threadIdx.x < L_SZ) bd_s[threadIdx.x] = bd[threadIdx.x];
  __syncthreads();

  long row = (long)blockIdx.x*128 + threadIdx.x;   // 0..32767
  const unsigned short* hp = hs + row*H_SZ;
  float acc[9];
#pragma unroll
  for (int jj = 0; jj < 9; ++jj) acc[jj] = 0.f;
  for (int k = 0; k < H_SZ; k += 8){
    uint4 v = *(const uint4*)(hp + k);
    const unsigned short* u = (const unsigned short*)&v;
#pragma unroll
    for (int l = 0; l < 8; ++l){
      float hf = bf2f(u[l]);
#pragma unroll
      for (int jj = 0; jj < 9; ++jj)
        acc[jj] = fmaf(hf, wd_s[(k + l)*L_SZ + jj], acc[jj]);
    }
  }
  float* op = out + row*L_SZ;
#pragma unroll
  for (int jj = 0; jj < 9; ++jj) op[jj] = acc[jj] + bd_s[jj];
}

// ---------------- CRF: score + forward algorithm ----------------
__global__ void k_crf(const float* __restrict__ logits, const int* __restrict__ labels,
                      const float* __restrict__ trans, const float* __restrict__ lensf,
                      float* __restrict__ out_ll)
{
  int b = blockIdx.x;
  int lane = threadIdx.x;             // 64 threads = 1 wave
  int len = (int)lensf[b];
  const float* lg  = logits + (long)b*T_SZ*L_SZ;
  const int*   lab = labels + b*T_SZ;

  float s = 0.f;
  for (int t = lane; t < T_SZ; t += 64){
    if (t < len){
      s += lg[t*L_SZ + lab[t]];
      if (t >= 1) s += trans[lab[t-1]*L_SZ + lab[t]];
    }
  }
  for (int off = 32; off; off >>= 1) s += __shfl_down(s, off, 64);

  float tr[9];
#pragma unroll
  for (int i = 0; i < 9; ++i) tr[i] = (lane < 9) ? trans[i*L_SZ + lane] : 0.f;
  float alpha = (lane < 9) ? lg[lane] : -1e30f;

  for (int t = 1; t < T_SZ; ++t){
    float tmp[9];
#pragma unroll
    for (int i = 0; i < 9; ++i){
      float ai = __shfl(alpha, i, 64);
      tmp[i] = ai + tr[i];
    }
    float m0 = fmaxf(fmaxf(tmp[0], tmp[1]), tmp[2]);
    float m1 = fmaxf(fmaxf(tmp[3], tmp[4]), tmp[5]);
    float m2 = fmaxf(fmaxf(tmp[6], tmp[7]), tmp[8]);
    float m  = fmaxf(fmaxf(m0, m1), m2);
    float e = 0.f;
#pragma unroll
    for (int i = 0; i < 9; ++i) e += __expf(tmp[i] - m);
    float lgv = (lane < 9) ? lg[t*L_SZ + lane] : 0.f;
    float nv = m + __logf(e) + lgv;
    if (t < len && lane < 9) alpha = nv;
  }

  float mm = (lane < 9) ? alpha : -1e30f;
  for (int off = 8; off; off >>= 1) mm = fmaxf(mm, __shfl_down(mm, off, 64));
  mm = __shfl(mm, 0, 64);
  float ee = (lane < 9) ? __expf(alpha - mm) : 0.f;
  for (int off = 8; off; off >>= 1) ee += __shfl_down(ee, off, 64);
  if (lane == 0) out_ll[b] = s - (mm + __logf(ee));
}

extern "C" void kernel_launch(void* const* d_in, const int* in_sizes, int n_in,
                              void* d_out, int out_size, void* d_ws, size_t ws_size,
                              hipStream_t stream)
{
  const int*   text   = (const int*)  d_in[0];
  const int*   labels = (const int*)  d_in[1];
  const float* embed  = (const float*)d_in[2];
  const float* Wx     = (const float*)d_in[3];
  const float* Wh     = (const float*)d_in[4];
  const float* bias   = (const float*)d_in[5];
  const float* Wd     = (const float*)d_in[6];
  const float* bd     = (const float*)d_in[7];
  const float* trans  = (const float*)d_in[8];

  float* out        = (float*)d_out;
  float* out_logits = out;
  float* out_lens   = out + LOGITS_N;
  float* out_ll     = out + LOGITS_N + B_SZ;

  unsigned short* hs = (unsigned short*)d_ws;

  k_reset <<<2048, 256, 0, stream>>>((unsigned long long*)hs);
  k_lens  <<<B_SZ, 256, 0, stream>>>(text, out_lens);
  k_lstm  <<<256, 256, 0, stream>>>(text, embed, Wx, Wh, bias, hs);
  k_logits<<<256, 128, 0, stream>>>(hs, Wd, bd, out_logits);
  k_crf   <<<B_SZ, 64, 0, stream>>>(out_logits, labels, trans, out_lens, out_ll);
}

// Round 7
// 1550.623 us; speedup vs baseline: 1.2994x; 1.0170x over previous
//
#include <hip/hip_runtime.h>
#include <hip/hip_bf16.h>

#define V_SZ 100000
#define E_SZ 128
#define H_SZ 512
#define L_SZ 9
#define B_SZ 64
#define T_SZ 512
#define G4   (4*H_SZ)

#define LOGITS_N (B_SZ*T_SZ*L_SZ)            // 294912
#define HS_BYTES ((size_t)B_SZ*T_SZ*H_SZ*2)  // 33554432
#define SENT32 0x7FC07FC0u
#define SENT64 0x7FC07FC07FC07FC0ull

typedef short bf16x8 __attribute__((ext_vector_type(8)));
typedef float f32x4  __attribute__((ext_vector_type(4)));

static __device__ __forceinline__ unsigned short f2bf(float x){
  unsigned int u = __builtin_bit_cast(unsigned int, x);
  unsigned int r = (u + 0x7fffu + ((u >> 16) & 1u)) >> 16;
  return (unsigned short)r;
}
static __device__ __forceinline__ float bf2f(unsigned short b){
  unsigned int u = ((unsigned int)b) << 16;
  return __builtin_bit_cast(float, u);
}
static __device__ __forceinline__ float sig_f(float x){
  return 1.f / (1.f + __expf(-x));
}
static __device__ __forceinline__ float tanh_f(float x){
  float a = fabsf(x);
  float e = __expf(-2.f * a);
  float t = (1.f - e) / (1.f + e);
  return copysignf(t, x);
}

// ---------------- reset hs to sentinel (graph replays don't re-poison) ------
__global__ void k_reset(unsigned long long* __restrict__ hs64){
  const long n = HS_BYTES / 8;
  for (long i = (long)blockIdx.x*256 + threadIdx.x; i < n; i += (long)gridDim.x*256)
    __hip_atomic_store(&hs64[i], SENT64, __ATOMIC_RELAXED, __HIP_MEMORY_SCOPE_AGENT);
}

// ---------------- lens ----------------
__global__ void k_lens(const int* __restrict__ text, float* __restrict__ out_lens){
  int b = blockIdx.x;
  int c = 0;
  for (int t = threadIdx.x; t < T_SZ; t += 256)
    c += (text[b*T_SZ + t] != 0);
  for (int off = 32; off; off >>= 1) c += __shfl_down(c, off, 64);
  __shared__ int sred[4];
  int w = threadIdx.x >> 6;
  if ((threadIdx.x & 63) == 0) sred[w] = c;
  __syncthreads();
  if (threadIdx.x == 0)
    out_lens[b] = (float)(sred[0] + sred[1] + sred[2] + sred[3]);
}

// ---------------- fused embed + xg + LSTM recurrence ----------------
// r6's proven structure, plus:
//  (1) x_t+1 prefetched during step t into the other parity buffer, so the
//      h-poll starts at step entry (embed-load chain off the critical path);
//  (2) 8B publishes (4 cols per u64 relaxed-agent store, data-is-flag).
// Permuted B-layout: B-col l16 -> (gate = l16&3, h-col = n0 + 4w + (l16>>2)).
__global__ __launch_bounds__(256, 1)
void k_lstm(const int* __restrict__ text, const float* __restrict__ embed,
            const float* __restrict__ Wx, const float* __restrict__ Wh,
            const float* __restrict__ bias, unsigned short* __restrict__ hs)
{
  const int g    = blockIdx.x & 7;     // group (intended XCD under round-robin)
  const int j    = blockIdx.x >> 3;    // 0..31 block-in-group
  const int n0   = j * 16;             // owned h-columns [n0, n0+16)
  const int tid  = threadIdx.x;
  const int w    = tid >> 6;           // wave id
  const int lane = tid & 63;
  const int q    = lane >> 4;
  const int l16  = lane & 15;
  const int gate = l16 & 3;            // B-col -> gate
  const int cq   = l16 >> 2;           // B-col -> col-in-wave 0..3

  __shared__ unsigned short h_lds[2][16*512];   // 2 x 16 KB, swizzled, rows 8-15 zero
  __shared__ unsigned short x_lds[2][16*128];   // 2 x 4 KB,  swizzled, rows 8-15 zero
  __shared__ int text_lds[8*T_SZ];              // 16 KB token table

  for (int i = tid; i < 2*16*512; i += 256) ((unsigned short*)h_lds)[i] = 0;
  for (int i = tid; i < 2*16*128; i += 256) ((unsigned short*)x_lds)[i] = 0;
  for (int i = tid; i < 8*T_SZ;   i += 256)
    text_lds[i] = text[(g*8 + (i >> 9))*T_SZ + (i & 511)];

  // ---- weight B-frags (permuted): W[(kk*32 + q*8 + jj)][gate*H + hcol] ----
  const int hcol = n0 + w*4 + cq;
  const int gcol = gate*H_SZ + hcol;
  bf16x8 Whf[16];
#pragma unroll
  for (int kk = 0; kk < 16; ++kk){
    bf16x8 v;
#pragma unroll
    for (int jj = 0; jj < 8; ++jj)
      v[jj] = (short)f2bf(Wh[(long)(kk*32 + q*8 + jj)*G4 + gcol]);
    Whf[kk] = v;
  }
  bf16x8 Wxf[4];
#pragma unroll
  for (int kk = 0; kk < 4; ++kk){
    bf16x8 v;
#pragma unroll
    for (int jj = 0; jj < 8; ++jj)
      v[jj] = (short)f2bf(Wx[(long)(kk*32 + q*8 + jj)*G4 + gcol]);
    Wxf[kk] = v;
  }
  const float biasv = bias[gcol];

  // c-state: rows q*4+rg of the wave's 4 columns (used for q<2);
  // redundant across the 4 gate-lanes of each column -> identical arithmetic.
  float cs[4] = {0.f, 0.f, 0.f, 0.f};
  const bool isPub = (gate == 0) && (cq == 0) && (q < 2);

  unsigned short* ppub[4];
#pragma unroll
  for (int rg = 0; rg < 4; ++rg)
    ppub[rg] = hs + ((long)(g*8 + q*4 + rg)*T_SZ)*H_SZ + n0 + w*4;

  // x-staging mapping (same every step)
  const int xr = tid >> 5;             // 0..7 (batch row)
  const int c4 = (tid & 31) * 4;       // f32 column
  const int cb = c4 * 2;               // byte col in LDS row
  unsigned short* xdst[2];
#pragma unroll
  for (int pb = 0; pb < 2; ++pb)
    xdst[pb] = (unsigned short*)((char*)x_lds[pb] + xr*256 + (cb ^ (xr << 4)));

  __syncthreads();   // zeros + text_lds visible

  // stage x for t=0 into x_lds[0] (ordered by the in-loop barrier at t=0)
  {
    int tok = text_lds[xr*T_SZ + 0];
    const float4 xv = *(const float4*)(embed + (long)tok*E_SZ + c4);
    unsigned short* pp = xdst[0];
    pp[0] = f2bf(xv.x); pp[1] = f2bf(xv.y); pp[2] = f2bf(xv.z); pp[3] = f2bf(xv.w);
  }

  for (int t = 0; t < T_SZ; ++t){
    const int par = t & 1;

    if (t > 0){
      // ---- poll h_{t-1} (data is the flag), then stage to LDS ----
      unsigned long long v[4];
      int it = 0; bool ok;
      do {
        ok = true;
#pragma unroll
        for (int c = 0; c < 4; ++c){
          int chunk = tid + 256*c;            // 0..1023
          int hr    = chunk >> 7;             // 0..7
          int k4    = chunk & 127;            // 8B chunk -> cols k4*4
          v[c] = __hip_atomic_load(
              (const unsigned long long*)(hs + ((long)(g*8 + hr)*T_SZ + (t-1))*H_SZ + k4*4),
              __ATOMIC_RELAXED, __HIP_MEMORY_SCOPE_AGENT);
        }
#pragma unroll
        for (int c = 0; c < 4; ++c){
          unsigned int lo = (unsigned int)v[c], hi = (unsigned int)(v[c] >> 32);
          ok = ok && (lo != SENT32) && (hi != SENT32);
        }
      } while (!ok && ++it < (1 << 20));
#pragma unroll
      for (int c = 0; c < 4; ++c){
        int chunk = tid + 256*c;
        int hr    = chunk >> 7;
        int k4    = chunk & 127;
        *(unsigned long long*)((char*)h_lds[par] + hr*1024 + ((k4*8) ^ (hr << 4))) = v[c];
      }
    }
    __syncthreads();   // the ONLY barrier: staging done; parity buffers make
                       // cross-step LDS write/read disjoint

    // ---- prefetch x_{t+1}: issue embed load now, LDS write at step end ----
    float4 xv; bool havex = (t + 1 < T_SZ);
    if (havex){
      int tok = text_lds[xr*T_SZ + t + 1];
      xv = *(const float4*)(embed + (long)tok*E_SZ + c4);
    }

    // ---- MFMA: gates = x_t @ Wx (+ h_{t-1} @ Wh) + b ----
    f32x4 acc0 = {biasv, biasv, biasv, biasv};
    f32x4 acc1 = {0.f, 0.f, 0.f, 0.f};
#pragma unroll
    for (int kk = 0; kk < 4; ++kk){
      bf16x8 a = *(const bf16x8*)((const char*)x_lds[par] + l16*256 + ((kk*64 + q*16) ^ (l16 << 4)));
      if (kk & 1) acc1 = __builtin_amdgcn_mfma_f32_16x16x32_bf16(a, Wxf[kk], acc1, 0, 0, 0);
      else        acc0 = __builtin_amdgcn_mfma_f32_16x16x32_bf16(a, Wxf[kk], acc0, 0, 0, 0);
    }
    if (t > 0){
#pragma unroll
      for (int kk = 0; kk < 16; ++kk){
        bf16x8 a = *(const bf16x8*)((const char*)h_lds[par] + l16*1024 + ((kk*64 + q*16) ^ (l16 << 4)));
        if (kk & 1) acc1 = __builtin_amdgcn_mfma_f32_16x16x32_bf16(a, Whf[kk], acc1, 0, 0, 0);
        else        acc0 = __builtin_amdgcn_mfma_f32_16x16x32_bf16(a, Whf[kk], acc0, 0, 0, 0);
      }
    }

    // ---- gates via quad shuffles; c,h; publish 8B (data-is-flag) ----
    // C/D: col = l16 -> (gate, cq); row = q*4+rg. xor-k neighbor holds gate^k.
#pragma unroll
    for (int rg = 0; rg < 4; ++rg){
      float v  = acc0[rg] + acc1[rg];
      float x1 = __shfl_xor(v, 1, 64);
      float x2 = __shfl_xor(v, 2, 64);
      float x3 = __shfl_xor(v, 3, 64);
      float gi = (gate==0)? v : (gate==1)? x1 : (gate==2)? x2 : x3;
      float gf = (gate==1)? v : (gate==0)? x1 : (gate==3)? x2 : x3;
      float gc = (gate==2)? v : (gate==3)? x1 : (gate==0)? x2 : x3;
      float go = (gate==3)? v : (gate==2)? x1 : (gate==1)? x2 : x3;
      cs[rg] = sig_f(gf)*cs[rg] + sig_f(gi)*tanh_f(gc);
      float hv = sig_f(go)*tanh_f(cs[rg]);
      unsigned int hb = (unsigned int)f2bf(hv);
      unsigned int pr  = (unsigned int)__shfl_xor((int)hb, 4, 64);   // col cq^1
      unsigned int pk  = hb | (pr << 16);                            // 2 cols
      unsigned int pk2 = (unsigned int)__shfl_xor((int)pk, 8, 64);   // cols cq^2
      unsigned long long p8 = (unsigned long long)pk
                            | ((unsigned long long)pk2 << 32);       // 4 cols
      if (isPub)
        __hip_atomic_store((unsigned long long*)ppub[rg], p8,
                           __ATOMIC_RELAXED, __HIP_MEMORY_SCOPE_AGENT);
    }
#pragma unroll
    for (int rg = 0; rg < 4; ++rg) ppub[rg] += H_SZ;

    // ---- write the prefetched x_{t+1} into the other parity buffer ----
    // (after barrier(t) on both producer and consumer sides -> race-free)
    if (havex){
      unsigned short* pp = xdst[par ^ 1];
      pp[0] = f2bf(xv.x); pp[1] = f2bf(xv.y); pp[2] = f2bf(xv.z); pp[3] = f2bf(xv.w);
    }
    // no trailing barrier: next iteration uses the OTHER parity buffers
  }
}

// ---------------- logits = hs @ Wd + bd ----------------
__global__ void k_logits(const unsigned short* __restrict__ hs,
                         const float* __restrict__ Wd, const float* __restrict__ bd,
                         float* __restrict__ out)
{
  __shared__ float wd_s[H_SZ*L_SZ];
  __shared__ float bd_s[L_SZ];
  for (int i = threadIdx.x; i < H_SZ*L_SZ; i += 128) wd_s[i] = Wd[i];
  if (threadIdx.x < L_SZ) bd_s[threadIdx.x] = bd[threadIdx.x];
  __syncthreads();

  long row = (long)blockIdx.x*128 + threadIdx.x;   // 0..32767
  const unsigned short* hp = hs + row*H_SZ;
  float acc[9];
#pragma unroll
  for (int jj = 0; jj < 9; ++jj) acc[jj] = 0.f;
  for (int k = 0; k < H_SZ; k += 8){
    uint4 v = *(const uint4*)(hp + k);
    const unsigned short* u = (const unsigned short*)&v;
#pragma unroll
    for (int l = 0; l < 8; ++l){
      float hf = bf2f(u[l]);
#pragma unroll
      for (int jj = 0; jj < 9; ++jj)
        acc[jj] = fmaf(hf, wd_s[(k + l)*L_SZ + jj], acc[jj]);
    }
  }
  float* op = out + row*L_SZ;
#pragma unroll
  for (int jj = 0; jj < 9; ++jj) op[jj] = acc[jj] + bd_s[jj];
}

// ---------------- CRF: score + forward algorithm ----------------
__global__ void k_crf(const float* __restrict__ logits, const int* __restrict__ labels,
                      const float* __restrict__ trans, const float* __restrict__ lensf,
                      float* __restrict__ out_ll)
{
  int b = blockIdx.x;
  int lane = threadIdx.x;             // 64 threads = 1 wave
  int len = (int)lensf[b];
  const float* lg  = logits + (long)b*T_SZ*L_SZ;
  const int*   lab = labels + b*T_SZ;

  float s = 0.f;
  for (int t = lane; t < T_SZ; t += 64){
    if (t < len){
      s += lg[t*L_SZ + lab[t]];
      if (t >= 1) s += trans[lab[t-1]*L_SZ + lab[t]];
    }
  }
  for (int off = 32; off; off >>= 1) s += __shfl_down(s, off, 64);

  float tr[9];
#pragma unroll
  for (int i = 0; i < 9; ++i) tr[i] = (lane < 9) ? trans[i*L_SZ + lane] : 0.f;
  float alpha = (lane < 9) ? lg[lane] : -1e30f;

  for (int t = 1; t < T_SZ; ++t){
    float tmp[9];
#pragma unroll
    for (int i = 0; i < 9; ++i){
      float ai = __shfl(alpha, i, 64);
      tmp[i] = ai + tr[i];
    }
    float m0 = fmaxf(fmaxf(tmp[0], tmp[1]), tmp[2]);
    float m1 = fmaxf(fmaxf(tmp[3], tmp[4]), tmp[5]);
    float m2 = fmaxf(fmaxf(tmp[6], tmp[7]), tmp[8]);
    float m  = fmaxf(fmaxf(m0, m1), m2);
    float e = 0.f;
#pragma unroll
    for (int i = 0; i < 9; ++i) e += __expf(tmp[i] - m);
    float lgv = (lane < 9) ? lg[t*L_SZ + lane] : 0.f;
    float nv = m + __logf(e) + lgv;
    if (t < len && lane < 9) alpha = nv;
  }

  float mm = (lane < 9) ? alpha : -1e30f;
  for (int off = 8; off; off >>= 1) mm = fmaxf(mm, __shfl_down(mm, off, 64));
  mm = __shfl(mm, 0, 64);
  float ee = (lane < 9) ? __expf(alpha - mm) : 0.f;
  for (int off = 8; off; off >>= 1) ee += __shfl_down(ee, off, 64);
  if (lane == 0) out_ll[b] = s - (mm + __logf(ee));
}

extern "C" void kernel_launch(void* const* d_in, const int* in_sizes, int n_in,
                              void* d_out, int out_size, void* d_ws, size_t ws_size,
                              hipStream_t stream)
{
  const int*   text   = (const int*)  d_in[0];
  const int*   labels = (const int*)  d_in[1];
  const float* embed  = (const float*)d_in[2];
  const float* Wx     = (const float*)d_in[3];
  const float* Wh     = (const float*)d_in[4];
  const float* bias   = (const float*)d_in[5];
  const float* Wd     = (const float*)d_in[6];
  const float* bd     = (const float*)d_in[7];
  const float* trans  = (const float*)d_in[8];

  float* out        = (float*)d_out;
  float* out_logits = out;
  float* out_lens   = out + LOGITS_N;
  float* out_ll     = out + LOGITS_N + B_SZ;

  unsigned short* hs = (unsigned short*)d_ws;

  k_reset <<<2048, 256, 0, stream>>>((unsigned long long*)hs);
  k_lens  <<<B_SZ, 256, 0, stream>>>(text, out_lens);
  k_lstm  <<<256, 256, 0, stream>>>(text, embed, Wx, Wh, bias, hs);
  k_logits<<<256, 128, 0, stream>>>(hs, Wd, bd, out_logits);
  k_crf   <<<B_SZ, 64, 0, stream>>>(out_logits, labels, trans, out_lens, out_ll);
}